// Round 2
// baseline (851.657 us; speedup 1.0000x reference)
//
#include <hip/hip_runtime.h>

#define ROWLEN 16384
#define NF4 (ROWLEN / 4)
#define KSEL 64u
#define CAP  2048u   // candidate buffer; ~10x max expected 12-bit bin population

// Order-preserving float -> u32 key (larger key == larger float; input NaN-free)
__device__ __forceinline__ unsigned f2k(float f) {
    unsigned u = __float_as_uint(f);
    return (u & 0x80000000u) ? ~u : (u | 0x80000000u);
}
__device__ __forceinline__ float k2f(unsigned k) {
    unsigned u = (k & 0x80000000u) ? (k ^ 0x80000000u) : ~k;
    return __uint_as_float(u);
}

__global__ __launch_bounds__(256, 4)
void sparsify_topk_kernel(const float* __restrict__ x, float* __restrict__ out) {
    const int t = threadIdx.x;
    const int row = blockIdx.x;
    const int lane = t & 63, w = t >> 6;

    // Transposed 12-bit histogram: bin b stored at hist[(b&15)*256 + (b>>4)].
    // Super-bin s (= b>>4) is then summed by thread s with stride-256 reads
    // (conflict-free); natural layout t*16+i would be a 32-way bank conflict.
    __shared__ unsigned hist[4096];
    __shared__ unsigned cand[CAP];
    __shared__ unsigned ncand;
    __shared__ unsigned wtot[4];
    __shared__ unsigned selPrefix, selK, tkeySh;

    // ---- Load row into registers as sortable keys (coalesced float4) ----
    const float4* xrow = (const float4*)(x + (size_t)row * ROWLEN);
    unsigned keys[64];
#pragma unroll
    for (int j = 0; j < 16; ++j) {
        float4 v = xrow[j * 256 + t];
        keys[4 * j + 0] = f2k(v.x);
        keys[4 * j + 1] = f2k(v.y);
        keys[4 * j + 2] = f2k(v.z);
        keys[4 * j + 3] = f2k(v.w);
    }

    // ---- Zero histogram / init ----
#pragma unroll
    for (int i = 0; i < 16; ++i) hist[i * 256 + t] = 0;
    if (t == 0) ncand = 0;
    __syncthreads();

    // ---- Build 12-bit histogram, unguarded ds_add (no return, no dep chain) ----
#pragma unroll
    for (int e = 0; e < 64; ++e) {
        unsigned b = keys[e] >> 20;                    // top 12 bits
        atomicAdd(&hist[(b & 15u) * 256u + (b >> 4)], 1u);
    }
    __syncthreads();

    // ---- Super-bin suffix scan: find 12-bit bin containing rank KSEL ----
    unsigned s = 0;
#pragma unroll
    for (int i = 0; i < 16; ++i) s += hist[i * 256 + t];   // super-bin t total

    unsigned incl = s;                                  // within-wave suffix sum
#pragma unroll
    for (int d = 1; d < 64; d <<= 1) {
        unsigned v = __shfl_down(incl, d);
        if (lane + d < 64) incl += v;
    }
    if (lane == 0) wtot[w] = incl;
    __syncthreads();

    unsigned above = incl - s;                          // strictly-above within wave
    for (int w2 = w + 1; w2 < 4; ++w2) above += wtot[w2];

    if (above < KSEL && above + s >= KSEL) {            // exactly one thread
        unsigned A = above;
#pragma unroll
        for (int i = 15; i >= 0; --i) {                 // top bin downward
            unsigned c = hist[i * 256 + t];
            if (A + c >= KSEL) { selPrefix = ((unsigned)t << 4) | (unsigned)i;
                                 selK = KSEL - A; break; }
            A += c;
        }
    }
    __syncthreads();

    // ---- Collect candidates matching the 12-bit prefix ----
    const unsigned pfx = selPrefix;
    const unsigned k2 = selK;
#pragma unroll
    for (int e = 0; e < 64; ++e) {
        if ((keys[e] >> 20) == pfx) {
            unsigned idx = atomicAdd(&ncand, 1u);
            if (idx < CAP) cand[idx] = keys[e];
        }
    }
    __syncthreads();

    // ---- Exact k2-th largest among candidates (broadcast reads, O(n^2)) ----
    unsigned n = ncand; if (n > CAP) n = CAP;
    for (unsigned i = t; i < n; i += 256) {
        unsigned ki = cand[i];
        unsigned gt = 0, ge = 0;
        for (unsigned j = 0; j < n; ++j) {
            unsigned kj = cand[j];
            gt += (kj > ki);
            ge += (kj >= ki);
        }
        if (gt < k2 && ge >= k2) tkeySh = ki;           // unique value; ties write same
    }
    __syncthreads();
    const unsigned tkey = tkeySh;

    // ---- Epilogue: mask in key space, reconstruct floats, coalesced store ----
    float4* orow = (float4*)out + (size_t)row * NF4;
#pragma unroll
    for (int j = 0; j < 16; ++j) {
        unsigned k0 = keys[4 * j + 0], k1 = keys[4 * j + 1];
        unsigned kk2 = keys[4 * j + 2], k3 = keys[4 * j + 3];
        float4 o;
        o.x = (k0 >= tkey) ? k2f(k0) : 0.0f;
        o.y = (k1 >= tkey) ? k2f(k1) : 0.0f;
        o.z = (kk2 >= tkey) ? k2f(kk2) : 0.0f;
        o.w = (k3 >= tkey) ? k2f(k3) : 0.0f;
        orow[j * 256 + t] = o;
    }
}

extern "C" void kernel_launch(void* const* d_in, const int* in_sizes, int n_in,
                              void* d_out, int out_size, void* d_ws, size_t ws_size,
                              hipStream_t stream) {
    const float* x = (const float*)d_in[0];
    float* out = (float*)d_out;
    const int rows = in_sizes[0] / ROWLEN;
    sparsify_topk_kernel<<<rows, 256, 0, stream>>>(x, out);
}